// Round 4
// baseline (260.950 us; speedup 1.0000x reference)
//
#include <hip/hip_runtime.h>

#define NCLS  5
#define NC    512
#define EPSF  1e-08f
#define PCOLS 2568          // 5*512 class sums + 5 counts + 3 pad
#define RED_G 8             // groups over partial rows in tree reduce
#define CB    ((PCOLS + 255) / 256)   // col-blocks in k_reduce (= 11)

// ---------------------------------------------------------------------------
// Kernel 1: per-row softmax + per-class accumulation.
// Wave owns a contiguous chunk of <=64 rows; targets preloaded (1/lane).
// 2-row software-pipelined loop: loads for rows r+2,r+3 are issued BEFORE
// processing rows r,r+1, so each wave always has memory requests in flight
// during its exp/shuffle/acc window. Per-block combine in LDS, then ONE
// coalesced plain-store of the block's partial row (no atomics, no memset).
// ---------------------------------------------------------------------------
__global__ __launch_bounds__(256) void k_accum(const float* __restrict__ inp,
                                               const long long* __restrict__ tgt,
                                               float* __restrict__ partial, // [nblocks][PCOLS]
                                               int B, int rows_pw) {
    __shared__ float lsum[NCLS * NC];   // 10 KiB
    __shared__ float lcnt[NCLS];
    for (int i = threadIdx.x; i < NCLS * NC; i += blockDim.x) lsum[i] = 0.0f;
    if (threadIdx.x < NCLS) lcnt[threadIdx.x] = 0.0f;
    __syncthreads();

    const int lane = threadIdx.x & 63;
    const int wib  = threadIdx.x >> 6;           // wave in block (0..3)
    const int gw   = blockIdx.x * 4 + wib;       // global wave id
    const int row0 = gw * rows_pw;
    int row_end = row0 + rows_pw;
    if (row_end > B) row_end = B;

    // preload this wave's targets: lane l holds class of row row0+l
    int tv = 0;
    if (lane < rows_pw && row0 + lane < B) tv = (int)tgt[row0 + lane];

    float acc[NCLS][8];
#pragma unroll
    for (int k = 0; k < NCLS; ++k)
#pragma unroll
        for (int j = 0; j < 8; ++j) acc[k][j] = 0.0f;
    float cnt[NCLS] = {0.f, 0.f, 0.f, 0.f, 0.f};

#define EXP4(v) v.x = __expf(v.x); v.y = __expf(v.y); v.z = __expf(v.z); v.w = __expf(v.w)

    // process rows R0,R1 held in (A0,B0),(A1,B1); classes T0,T1
#define PROC2(A0, B0, A1, B1, T0, T1)                                          \
    {                                                                          \
        EXP4(A0); EXP4(B0); EXP4(A1); EXP4(B1);                                \
        float s0_ = ((A0.x + A0.y) + (A0.z + A0.w)) +                          \
                    ((B0.x + B0.y) + (B0.z + B0.w));                           \
        float s1_ = ((A1.x + A1.y) + (A1.z + A1.w)) +                          \
                    ((B1.x + B1.y) + (B1.z + B1.w));                           \
        _Pragma("unroll")                                                      \
        for (int off_ = 32; off_ > 0; off_ >>= 1) {                            \
            s0_ += __shfl_xor(s0_, off_, 64);                                  \
            s1_ += __shfl_xor(s1_, off_, 64);                                  \
        }                                                                      \
        const float inv0_ = 1.0f / s0_;                                        \
        const float inv1_ = 1.0f / s1_;                                        \
        _Pragma("unroll")                                                      \
        for (int k = 0; k < NCLS; ++k) {                                       \
            const float w0_ = (T0 == k) ? inv0_ : 0.0f;                        \
            const float w1_ = (T1 == k) ? inv1_ : 0.0f;                        \
            cnt[k] += ((T0 == k) ? 1.0f : 0.0f) + ((T1 == k) ? 1.0f : 0.0f);   \
            acc[k][0] += A0.x * w0_ + A1.x * w1_;                              \
            acc[k][1] += A0.y * w0_ + A1.y * w1_;                              \
            acc[k][2] += A0.z * w0_ + A1.z * w1_;                              \
            acc[k][3] += A0.w * w0_ + A1.w * w1_;                              \
            acc[k][4] += B0.x * w0_ + B1.x * w1_;                              \
            acc[k][5] += B0.y * w0_ + B1.y * w1_;                              \
            acc[k][6] += B0.z * w0_ + B1.z * w1_;                              \
            acc[k][7] += B0.w * w0_ + B1.w * w1_;                              \
        }                                                                      \
    }

    int r = row0;
    float4 ca0, cb0, ca1, cb1;
    const bool have2 = (r + 1 < row_end);
    if (have2) {
        const float4* p = (const float4*)(inp + (size_t)r * NC);
        ca0 = p[lane];       cb0 = p[lane + 64];    // row r
        ca1 = p[lane + 128]; cb1 = p[lane + 192];   // row r+1
    }
    for (; r + 3 < row_end; r += 2) {
        // prefetch next pair BEFORE consuming current pair
        const float4* pn = (const float4*)(inp + (size_t)(r + 2) * NC);
        float4 na0 = pn[lane];       float4 nb0 = pn[lane + 64];
        float4 na1 = pn[lane + 128]; float4 nb1 = pn[lane + 192];

        const int t0 = __builtin_amdgcn_readlane(tv, (r - row0) + 0);
        const int t1 = __builtin_amdgcn_readlane(tv, (r - row0) + 1);
        PROC2(ca0, cb0, ca1, cb1, t0, t1);

        ca0 = na0; cb0 = nb0; ca1 = na1; cb1 = nb1;
    }
    if (r + 1 < row_end) {   // drain the pipelined pair
        const int t0 = __builtin_amdgcn_readlane(tv, (r - row0) + 0);
        const int t1 = __builtin_amdgcn_readlane(tv, (r - row0) + 1);
        PROC2(ca0, cb0, ca1, cb1, t0, t1);
        r += 2;
    }
    for (; r < row_end; ++r) {   // odd tail row
        const float4* p = (const float4*)(inp + (size_t)r * NC);
        float4 a0 = p[lane];
        float4 b0 = p[lane + 64];
        const int t0 = __builtin_amdgcn_readlane(tv, r - row0);
        EXP4(a0); EXP4(b0);
        float s0 = ((a0.x + a0.y) + (a0.z + a0.w)) + ((b0.x + b0.y) + (b0.z + b0.w));
#pragma unroll
        for (int off = 32; off > 0; off >>= 1) s0 += __shfl_xor(s0, off, 64);
        const float inv0 = 1.0f / s0;
#pragma unroll
        for (int k = 0; k < NCLS; ++k) {
            const float w = (t0 == k) ? inv0 : 0.0f;
            cnt[k] += (t0 == k) ? 1.0f : 0.0f;
            acc[k][0] += a0.x * w; acc[k][1] += a0.y * w;
            acc[k][2] += a0.z * w; acc[k][3] += a0.w * w;
            acc[k][4] += b0.x * w; acc[k][5] += b0.y * w;
            acc[k][6] += b0.z * w; acc[k][7] += b0.w * w;
        }
    }
#undef PROC2
#undef EXP4

    // wave -> LDS
#pragma unroll
    for (int k = 0; k < NCLS; ++k) {
#pragma unroll
        for (int j = 0; j < 4; ++j) {
            atomicAdd(&lsum[k * NC + 4 * lane + j],       acc[k][j]);
            atomicAdd(&lsum[k * NC + 256 + 4 * lane + j], acc[k][4 + j]);
        }
    }
    if (lane == 0) {
#pragma unroll
        for (int k = 0; k < NCLS; ++k) atomicAdd(&lcnt[k], cnt[k]);
    }
    __syncthreads();

    // block -> private partial row (plain coalesced stores; no init needed)
    float* prow = partial + (size_t)blockIdx.x * PCOLS;
    for (int i = threadIdx.x; i < PCOLS; i += blockDim.x) {
        float v;
        if (i < NCLS * NC)           v = lsum[i];
        else if (i < NCLS * NC + 5)  v = lcnt[i - NCLS * NC];
        else                         v = 0.0f;
        prow[i] = v;
    }
}

// ---------------------------------------------------------------------------
// Kernel 2: tree-reduce partial rows: stage2[g][col] = sum over group g.
// Coalesced: consecutive threads read consecutive columns.
// ---------------------------------------------------------------------------
__global__ __launch_bounds__(256) void k_reduce(const float* __restrict__ partial,
                                                float* __restrict__ stage2,  // [RED_G][PCOLS]
                                                int PB) {
    const int g   = blockIdx.x / CB;
    const int cb  = blockIdx.x % CB;
    const int col = cb * 256 + threadIdx.x;
    if (col >= PCOLS) return;
    const int per = (PB + RED_G - 1) / RED_G;
    int b0 = g * per;
    int b1 = b0 + per; if (b1 > PB) b1 = PB;
    float s = 0.0f;
    for (int b = b0; b < b1; ++b) s += partial[(size_t)b * PCOLS + col];
    stage2[g * PCOLS + col] = s;
}

// ---------------------------------------------------------------------------
// Kernel 3: centers = sums/max(cnt,1); loss = EPS + (1-mse01) + (1-mse23)
// ---------------------------------------------------------------------------
__global__ __launch_bounds__(512) void k_final(const float* __restrict__ stage2,
                                               float* __restrict__ out) {
    __shared__ float red[16];
    __shared__ float csh[4];
    const int tid = threadIdx.x;   // 0..511

    if (tid < 4) {
        float c = 0.0f;
#pragma unroll
        for (int g = 0; g < RED_G; ++g) c += stage2[g * PCOLS + NCLS * NC + tid];
        csh[tid] = fmaxf(c, 1.0f);
    }
    __syncthreads();
    const float r0 = 1.0f / csh[0];
    const float r1 = 1.0f / csh[1];
    const float r2 = 1.0f / csh[2];
    const float r3 = 1.0f / csh[3];

    float s0 = 0.f, s1 = 0.f, s2 = 0.f, s3 = 0.f;
#pragma unroll
    for (int g = 0; g < RED_G; ++g) {
        const float* sg = stage2 + g * PCOLS;
        s0 += sg[0 * NC + tid];
        s1 += sg[1 * NC + tid];
        s2 += sg[2 * NC + tid];
        s3 += sg[3 * NC + tid];
    }
    const float d01 = s0 * r0 - s1 * r1;
    const float d23 = s2 * r2 - s3 * r3;
    float q01 = d01 * d01;
    float q23 = d23 * d23;
#pragma unroll
    for (int off = 32; off > 0; off >>= 1) {
        q01 += __shfl_xor(q01, off, 64);
        q23 += __shfl_xor(q23, off, 64);
    }
    const int w = tid >> 6;
    if ((tid & 63) == 0) { red[w] = q01; red[8 + w] = q23; }
    __syncthreads();
    if (tid == 0) {
        float a = 0.f, b = 0.f;
#pragma unroll
        for (int i = 0; i < 8; ++i) { a += red[i]; b += red[8 + i]; }
        const float mse01 = a * (1.0f / (float)NC);
        const float mse23 = b * (1.0f / (float)NC);
        out[0] = EPSF + (1.0f - mse01) + (1.0f - mse23);
    }
}

extern "C" void kernel_launch(void* const* d_in, const int* in_sizes, int n_in,
                              void* d_out, int out_size, void* d_ws, size_t ws_size,
                              hipStream_t stream) {
    const float*     inp = (const float*)d_in[0];
    const long long* tgt = (const long long*)d_in[1];   // int64 targets
    float* out = (float*)d_out;
    const int B = in_sizes[1];

    const int ROWS_PW = 32;                       // <=64 (target preload limit)
    const int waves   = (B + ROWS_PW - 1) / ROWS_PW;   // 8192 for B=262144
    const int blocks  = (waves + 3) / 4;               // 2048

    float* partial = (float*)d_ws;                         // [blocks][PCOLS]
    float* stage2  = partial + (size_t)blocks * PCOLS;     // [RED_G][PCOLS]

    k_accum<<<blocks, 256, 0, stream>>>(inp, tgt, partial, B, ROWS_PW);
    k_reduce<<<RED_G * CB, 256, 0, stream>>>(partial, stage2, blocks);
    k_final<<<1, 512, 0, stream>>>(stage2, out);
}

// Round 5
// 125.694 us; speedup vs baseline: 2.0761x; 2.0761x over previous
//
#include <hip/hip_runtime.h>

#define NCLS 4              // only classes 0-3 affect the loss (centers[4] unused)
#define NC   512
#define EPSF 1e-08f

// ---------------------------------------------------------------------------
// Kernel 1: per-row softmax + per-class accumulation, classes 0-3 ONLY.
// Each wave owns 64 contiguous rows. It preloads its 64 targets (1/lane),
// builds a wave-uniform ballot mask of rows with t<4, and processes ONLY
// those rows (t==4 rows are never read: -20% HBM traffic). Set-bit iteration
// two rows at a time; all control flow is wave-uniform scalar ops.
// Per-class sums in registers acc[4][8]; counts via popcount(ballot)
// (exact, once per wave). Block-level LDS combine, then one global
// atomicAdd pass per block.
// No max-subtract: inputs ~N(0,1), fp32 exp is safe and softmax is
// shift-invariant; threshold has orders of magnitude of margin.
// ---------------------------------------------------------------------------
__global__ __launch_bounds__(256) void k_accum(const float* __restrict__ inp,
                                               const int*   __restrict__ tgt2, // int64 viewed as int pairs
                                               float* __restrict__ sums,   // [NCLS*NC]
                                               float* __restrict__ cnts,   // [NCLS]
                                               int B) {
    __shared__ float lsum[NCLS * NC];   // 8 KiB
    __shared__ float lcnt[NCLS];
    for (int i = threadIdx.x; i < NCLS * NC; i += blockDim.x) lsum[i] = 0.0f;
    if (threadIdx.x < NCLS) lcnt[threadIdx.x] = 0.0f;
    __syncthreads();

    const int lane = threadIdx.x & 63;
    const int wib  = threadIdx.x >> 6;            // wave in block (0..3)
    const int gw   = blockIdx.x * 4 + wib;        // global wave id
    const int row0 = gw * 64;                     // contiguous 64-row chunk

    // lane l holds target of row row0+l (low dword of the int64)
    int tv = NCLS;                                // sentinel: out-of-range/skip
    if (row0 + lane < B) tv = tgt2[2 * (size_t)(row0 + lane)];

    unsigned long long mask = __ballot(tv < NCLS);
    float cntv[NCLS];
#pragma unroll
    for (int k = 0; k < NCLS; ++k)
        cntv[k] = (float)__popcll(__ballot(tv == k));

    float acc[NCLS][8];
#pragma unroll
    for (int k = 0; k < NCLS; ++k)
#pragma unroll
        for (int j = 0; j < 8; ++j) acc[k][j] = 0.0f;

#define EXP4(v) v.x = __expf(v.x); v.y = __expf(v.y); v.z = __expf(v.z); v.w = __expf(v.w)

    while (mask) {
        const int i0 = __builtin_ctzll(mask); mask &= mask - 1;
        if (mask) {
            // --- two kept rows ---
            const int i1 = __builtin_ctzll(mask); mask &= mask - 1;
            const float4* p0 = (const float4*)(inp + (size_t)(row0 + i0) * NC);
            const float4* p1 = (const float4*)(inp + (size_t)(row0 + i1) * NC);
            float4 a0 = p0[lane]; float4 b0 = p0[lane + 64];
            float4 a1 = p1[lane]; float4 b1 = p1[lane + 64];
            const int t0 = __builtin_amdgcn_readlane(tv, i0);
            const int t1 = __builtin_amdgcn_readlane(tv, i1);

            EXP4(a0); EXP4(b0); EXP4(a1); EXP4(b1);
            float s0 = ((a0.x + a0.y) + (a0.z + a0.w)) + ((b0.x + b0.y) + (b0.z + b0.w));
            float s1 = ((a1.x + a1.y) + (a1.z + a1.w)) + ((b1.x + b1.y) + (b1.z + b1.w));
#pragma unroll
            for (int off = 32; off > 0; off >>= 1) {
                s0 += __shfl_xor(s0, off, 64);
                s1 += __shfl_xor(s1, off, 64);
            }
            const float inv0 = 1.0f / s0;
            const float inv1 = 1.0f / s1;
#pragma unroll
            for (int k = 0; k < NCLS; ++k) {
                const float w0 = (t0 == k) ? inv0 : 0.0f;
                const float w1 = (t1 == k) ? inv1 : 0.0f;
                acc[k][0] += a0.x * w0 + a1.x * w1;
                acc[k][1] += a0.y * w0 + a1.y * w1;
                acc[k][2] += a0.z * w0 + a1.z * w1;
                acc[k][3] += a0.w * w0 + a1.w * w1;
                acc[k][4] += b0.x * w0 + b1.x * w1;
                acc[k][5] += b0.y * w0 + b1.y * w1;
                acc[k][6] += b0.z * w0 + b1.z * w1;
                acc[k][7] += b0.w * w0 + b1.w * w1;
            }
        } else {
            // --- single leftover row ---
            const float4* p0 = (const float4*)(inp + (size_t)(row0 + i0) * NC);
            float4 a0 = p0[lane]; float4 b0 = p0[lane + 64];
            const int t0 = __builtin_amdgcn_readlane(tv, i0);
            EXP4(a0); EXP4(b0);
            float s0 = ((a0.x + a0.y) + (a0.z + a0.w)) + ((b0.x + b0.y) + (b0.z + b0.w));
#pragma unroll
            for (int off = 32; off > 0; off >>= 1) s0 += __shfl_xor(s0, off, 64);
            const float inv0 = 1.0f / s0;
#pragma unroll
            for (int k = 0; k < NCLS; ++k) {
                const float w = (t0 == k) ? inv0 : 0.0f;
                acc[k][0] += a0.x * w; acc[k][1] += a0.y * w;
                acc[k][2] += a0.z * w; acc[k][3] += a0.w * w;
                acc[k][4] += b0.x * w; acc[k][5] += b0.y * w;
                acc[k][6] += b0.z * w; acc[k][7] += b0.w * w;
            }
        }
    }
#undef EXP4

    // wave -> LDS
#pragma unroll
    for (int k = 0; k < NCLS; ++k) {
#pragma unroll
        for (int j = 0; j < 4; ++j) {
            atomicAdd(&lsum[k * NC + 4 * lane + j],       acc[k][j]);
            atomicAdd(&lsum[k * NC + 256 + 4 * lane + j], acc[k][4 + j]);
        }
    }
    if (lane == 0) {
#pragma unroll
        for (int k = 0; k < NCLS; ++k) atomicAdd(&lcnt[k], cntv[k]);
    }
    __syncthreads();

    // block -> global
    for (int i = threadIdx.x; i < NCLS * NC; i += blockDim.x)
        atomicAdd(&sums[i], lsum[i]);
    if (threadIdx.x < NCLS)
        atomicAdd(&cnts[threadIdx.x], lcnt[threadIdx.x]);
}

// ---------------------------------------------------------------------------
// Kernel 2: centers = sums / max(cnt,1); loss = EPS + (1-mse01) + (1-mse23)
// ---------------------------------------------------------------------------
__global__ void k_final(const float* __restrict__ sums,
                        const float* __restrict__ cnts,
                        float* __restrict__ out) {
    const int lane = threadIdx.x;   // 0..63
    const float r0 = 1.0f / fmaxf(cnts[0], 1.0f);
    const float r1 = 1.0f / fmaxf(cnts[1], 1.0f);
    const float r2 = 1.0f / fmaxf(cnts[2], 1.0f);
    const float r3 = 1.0f / fmaxf(cnts[3], 1.0f);

    float s01 = 0.0f, s23 = 0.0f;
#pragma unroll
    for (int j = 0; j < 8; ++j) {
        const int col = lane * 8 + j;
        const float d01 = sums[0 * NC + col] * r0 - sums[1 * NC + col] * r1;
        const float d23 = sums[2 * NC + col] * r2 - sums[3 * NC + col] * r3;
        s01 += d01 * d01;
        s23 += d23 * d23;
    }
#pragma unroll
    for (int off = 32; off > 0; off >>= 1) {
        s01 += __shfl_xor(s01, off, 64);
        s23 += __shfl_xor(s23, off, 64);
    }
    if (lane == 0) {
        const float mse01 = s01 * (1.0f / (float)NC);
        const float mse23 = s23 * (1.0f / (float)NC);
        out[0] = EPSF + (1.0f - mse01) + (1.0f - mse23);
    }
}

extern "C" void kernel_launch(void* const* d_in, const int* in_sizes, int n_in,
                              void* d_out, int out_size, void* d_ws, size_t ws_size,
                              hipStream_t stream) {
    const float* inp  = (const float*)d_in[0];
    const int*   tgt2 = (const int*)d_in[1];    // int64 targets viewed as int pairs
    float* out = (float*)d_out;
    const int B = in_sizes[1];

    float* sums = (float*)d_ws;                 // [NCLS*NC]
    float* cnts = sums + NCLS * NC;             // [NCLS]
    hipMemsetAsync(d_ws, 0, (NCLS * NC + NCLS) * sizeof(float), stream);

    const int waves  = (B + 63) / 64;           // 4096 for B=262144
    const int blocks = (waves + 3) / 4;         // 1024 (4 waves/block)
    k_accum<<<blocks, 256, 0, stream>>>(inp, tgt2, sums, cnts, B);
    k_final<<<1, 64, 0, stream>>>(sums, cnts, out);
}